// Round 3
// baseline (290.321 us; speedup 1.0000x reference)
//
#include <hip/hip_runtime.h>
#include <math.h>

#define BB 16
#define CC 64
#define NN 2048
#define KK 8
#define CAND 16          // phase-1 candidates (exact top-8 subset; validated R3/R6/R7/R10-R17)
#define QB 8             // queries per item (one per wave); keys LDS = QB*NN*4 = 64 KB
#define NT (QB * 64)     // 512 threads
#define MPW (NN / QB)    // 256 m-points per wave
#define TPW (MPW / 32)   // 8 col-tiles of 32 m-points per wave
#define NTILE (NN / 32)  // 64 m-tiles per batch
#define DPL 32           // keys per lane in select

typedef unsigned long long u64;
typedef unsigned short u16;
typedef __attribute__((ext_vector_type(8)))  short short8;   // 8 bf16 = 4 VGPRs (MFMA A/B frag)
typedef __attribute__((ext_vector_type(16))) float f32x16;   // MFMA 32x32 C/D frag

// order-preserving fp32 -> u32 flip: ascending uint == ascending float
__device__ __forceinline__ unsigned ordflip(float f) {
    unsigned u = __float_as_uint(f);
    return u ^ ((u & 0x80000000u) ? 0xFFFFFFFFu : 0x80000000u);
}
// inverse (on the masked high bits): recover approximate r from a packed key
__device__ __forceinline__ float unflip(unsigned k) {
    unsigned u = k & 0xFFFFF800u;
    u ^= (u & 0x80000000u) ? 0x80000000u : 0xFFFFFFFFu;
    return __uint_as_float(u);
}

// ---- cross-lane helpers: DPP for offsets inside a 16-lane row, bpermute beyond ----
template<int C>
__device__ __forceinline__ unsigned dppu(unsigned v) {
    return (unsigned)__builtin_amdgcn_update_dpp(0, (int)v, C, 0xF, 0xF, true);
}
template<int OFF>
__device__ __forceinline__ unsigned shx(unsigned v) {
    if constexpr (OFF == 1)       return dppu<0xB1>(v);    // quad_perm xor 1
    else if constexpr (OFF == 2)  return dppu<0x4E>(v);    // quad_perm xor 2
    else if constexpr (OFF == 7)  return dppu<0x141>(v);   // row_half_mirror = xor 7
    else if constexpr (OFF == 15) return dppu<0x140>(v);   // row_mirror      = xor 15
    else return (unsigned)__shfl_xor((int)v, OFF, 64);
}
template<int C>
__device__ __forceinline__ double dppd(double v) {
    unsigned long long u = (unsigned long long)__double_as_longlong(v);
    int lo = __builtin_amdgcn_update_dpp(0, (int)(u & 0xffffffffull), C, 0xF, 0xF, true);
    int hi = __builtin_amdgcn_update_dpp(0, (int)(u >> 32),           C, 0xF, 0xF, true);
    return __longlong_as_double((long long)(((unsigned long long)(unsigned)hi << 32) | (unsigned)lo));
}

// ascending bitonic cleanup of a bitonic 16-sequence (j = 8,4,2,1)
__device__ __forceinline__ void clean16(unsigned k[CAND]) {
#define CMPEX(a_, b_) { unsigned lo = k[a_] < k[b_] ? k[a_] : k[b_]; \
                        unsigned hi = k[a_] < k[b_] ? k[b_] : k[a_]; k[a_] = lo; k[b_] = hi; }
    CMPEX(0,8) CMPEX(1,9) CMPEX(2,10) CMPEX(3,11) CMPEX(4,12) CMPEX(5,13) CMPEX(6,14) CMPEX(7,15)
    CMPEX(0,4) CMPEX(1,5) CMPEX(2,6)  CMPEX(3,7)  CMPEX(8,12) CMPEX(9,13) CMPEX(10,14) CMPEX(11,15)
    CMPEX(0,2) CMPEX(1,3) CMPEX(4,6)  CMPEX(5,7)  CMPEX(8,10) CMPEX(9,11) CMPEX(12,14) CMPEX(13,15)
    CMPEX(0,1) CMPEX(2,3) CMPEX(4,5)  CMPEX(6,7)  CMPEX(8,9)  CMPEX(10,11) CMPEX(12,13) CMPEX(14,15)
#undef CMPEX
}

// one butterfly merge step: my sorted-16 vs partner's sorted-16 -> top-16 of union, sorted
template<int OFF>
__device__ __forceinline__ void merge16(unsigned k[CAND]) {
    unsigned pk[CAND];
#pragma unroll
    for (int j = 0; j < CAND; ++j) pk[j] = shx<OFF>(k[j]);
#pragma unroll
    for (int j = 0; j < CAND; ++j) {
        unsigned b2_ = pk[CAND - 1 - j];
        k[j] = (k[j] < b2_) ? k[j] : b2_;
    }
    clean16(k);
}

// xx[b,n] = sum_c x[b,c,n]^2  (fp32 proxy only — phase 2 rescores exactly when needed)
__global__ __launch_bounds__(256) void compute_xx(const float* __restrict__ x,
                                                  float* __restrict__ xx) {
    int t = blockIdx.x * 256 + threadIdx.x;      // t in [0, B*N)
    int b = t >> 11, n = t & (NN - 1);
    const float* xb = x + b * (CC * NN) + n;
    float s = 0.f;
#pragma unroll
    for (int c = 0; c < CC; ++c) { float v = xb[c * NN]; s = fmaf(v, v, s); }
    xx[t] = s;
}

// Pre-swizzled split-bf16 MFMA operand store (R2): bswz unit index
// ((b*64 + tt)*8 + p*4 + ks)*64 + lane holds the EXACT 16B (8 bf16) that
// wave-lane `lane` consumes for m-tile tt, pass p (0=hi,1=lo), k-step ks:
// point n = tt*32 + (lane&31), channels ks*16 + (lane>>5)*8 .. +7.
__global__ __launch_bounds__(256) void prep_bswz(const float* __restrict__ x,
                                                 u16* __restrict__ bswz) {
    const int t = blockIdx.x * 256 + threadIdx.x;   // [0, B*NTILE*8*64)
    const int lane = t & 63;
    const int ks   = (t >> 6) & 3;
    const int p    = (t >> 8) & 1;
    const int tt   = (t >> 9) & (NTILE - 1);
    const int b    = t >> 15;
    const int n    = tt * 32 + (lane & 31);
    const int c0   = ks * 16 + (lane >> 5) * 8;
    const float* src = x + b * (CC * NN) + n;
    unsigned o[8];
#pragma unroll
    for (int i = 0; i < 8; ++i) {
        const float v = src[(c0 + i) * NN];           // 32 consecutive lanes -> 128B contiguous
        unsigned u = __float_as_uint(v);
        unsigned hb = (u + 0x7FFFu + ((u >> 16) & 1u)) >> 16;       // RNE -> bf16 (hi)
        if (p == 0) {
            o[i] = hb;
        } else {
            const float vl = v - __uint_as_float(hb << 16);         // exact residual
            unsigned u2 = __float_as_uint(vl);
            o[i] = (u2 + 0x7FFFu + ((u2 >> 16) & 1u)) >> 16;        // RNE -> bf16 (lo)
        }
    }
    *(uint4*)(bswz + (size_t)t * 8) =
        make_uint4(o[0] | (o[1] << 16), o[2] | (o[3] << 16),
                   o[4] | (o[5] << 16), o[6] | (o[7] << 16));       // coalesced 16B store
}

// R3: two-item in-wave pipeline. Each block handles query groups n0 and n0+8
// of one batch. Item1's phase-A tiles are hand-interleaved with item0's sort
// chunks (loads -> sort chunk -> MFMA+epi), so in-order wave execution fills
// phase-A's memory latency with sort VALU and vice versa. Item1's B-fragment
// reads hit L1/L2 (same addresses as item0). Keys LDS is free during the
// fused region because item0's keys were register-loaded before the barrier.
__global__ __launch_bounds__(NT, 4) void knn_upsample(const float* __restrict__ x,
                                                      const float* __restrict__ xxg,
                                                      const u16* __restrict__ bswz,
                                                      float* __restrict__ out) {
    __shared__ unsigned keys[QB][NN];   // 64 KB

    const int tid  = threadIdx.x;
    const int w    = tid >> 6;                 // wave id = query id within item
    const int lane = tid & 63;
    const int blk  = blockIdx.x;

    // XCD-aware batch affinity (R13): 2048 blocks round-robin to 8 XCDs;
    // pin XCD x to batches {2x, 2x+1}.
    const int xcd = blk & 7;
    const int pj  = blk >> 3;                  // [0, 256)
    const int b   = 2 * xcd + (pj >> 7);       // batch
    const int jq  = pj & 127;                  // pair index within batch
    const int n0a = jq << 4;                   // item0 query group
    const int n0b = n0a + 8;                   // item1 query group
    const float* xb = x + b * (CC * NN);

    const int col = lane & 31;                 // MFMA row/col index
    const int h   = lane >> 5;                 // k-half (channels 8h..8h+7 of each k-step)
    const int mbase = w * MPW;                 // 256 m-points per wave (tiles w*8 .. w*8+7)
    const u16* bp = bswz + (((size_t)b * NTILE + w * TPW) * 8) * 64 * 8 + lane * 8;
    const float* xxp = xxg + (b << 11);

    // ---------------- phase-A building blocks ----------------
    short8 bhv[4], blv[4];
    auto tile_loads = [&](int t8) {
#pragma unroll
        for (int ks = 0; ks < 4; ++ks) {
            bhv[ks] = *(const short8*)(bp + ((size_t)(t8 * 8 + ks)     * 64) * 8);
            blv[ks] = *(const short8*)(bp + ((size_t)(t8 * 8 + 4 + ks) * 64) * 8);
        }
    };
    auto load_afrag = [&](short8 af[4], int n0x) {
        const int qi = col & 7;                // query row within the 8-query group
        const int p  = (col >> 3) & 1;         // 0 = hi rows, 1 = lo rows (zeroed if col>=16)
        const int nq = n0x + qi;
        const u16* ap = bswz + ((((size_t)b * NTILE + (nq >> 5)) * 8 + p * 4) * 64
                                + h * 32 + (nq & 31)) * 8;
#pragma unroll
        for (int ks = 0; ks < 4; ++ks) {
            short8 av = *(const short8*)(ap + (size_t)ks * 64 * 8);
            if (col >= 16) {
#pragma unroll
                for (int i2 = 0; i2 < 8; ++i2) av[i2] = 0;
            }
            af[ks] = av;
        }
    };
    // C/D layout (HW-verified m74/m101 + R1/R2 pass): col=lane&31,
    // row=(reg&3)+8*(reg>>2)+4*(lane>>5) -> lane half h holds hi AND lo
    // products of q=4h+r in regs r and r+4.
    auto tile_mfma_epi = [&](int t8, const short8 af[4], int n0x) {
        f32x16 acc1, acc2;                     // acc1: q*m_hi, acc2: q*m_lo
#pragma unroll
        for (int i2 = 0; i2 < 16; ++i2) { acc1[i2] = 0.f; acc2[i2] = 0.f; }
#pragma unroll
        for (int ks = 0; ks < 4; ++ks) {       // K=64 in 4 steps of 16
            acc1 = __builtin_amdgcn_mfma_f32_32x32x16_bf16(af[ks], bhv[ks], acc1, 0, 0, 0);
            acc2 = __builtin_amdgcn_mfma_f32_32x32x16_bf16(af[ks], blv[ks], acc2, 0, 0, 0);
        }
        const int m = mbase + t8 * 32 + col;
        const float xxm = xxp[m];
#pragma unroll
        for (int r = 0; r < 4; ++r) {
            const int q = 4 * h + r;           // lane half h owns queries 4h..4h+3
            const float I = (acc1[r] + acc1[r + 4]) + (acc2[r] + acc2[r + 4]);
            const float rr = fmaf(-2.f, I, xxm);
            unsigned u = __float_as_uint(rr);
            u ^= ((u & 0x80000000u) ? 0xFFFFFFFFu : 0x80000000u);
            const unsigned kpack = (u & 0xFFFFF800u) | (unsigned)m;
            keys[q][m] = (m == n0x + q) ? 0xFFFFFFFFu : kpack;   // exclude self
        }
    };

    // ---------------- select building blocks (verbatim R2 logic, chunked) ----------------
    unsigned key[DPL];
    auto regload = [&]() {
#pragma unroll
        for (int t = 0; t < 8; ++t) {          // contiguous uint4 reads (ds_read_b128)
            uint4 kv = *(const uint4*)(&keys[w][256 * t + 4 * lane]);
            key[4 * t] = kv.x; key[4 * t + 1] = kv.y; key[4 * t + 2] = kv.z; key[4 * t + 3] = kv.w;
        }
    };
    auto sort8_grp = [&](int blk4) {           // bitonic sort-8 of group blk4 (asc,desc,asc,desc)
        const int base = blk4 * 8;
        const bool asc = (blk4 & 1) == 0;
#pragma unroll
        for (int k = 2; k <= 8; k <<= 1) {
#pragma unroll
            for (int jj = k >> 1; jj > 0; jj >>= 1) {
#pragma unroll
                for (int i = 0; i < 8; ++i) {
                    int l = i ^ jj;
                    if (l > i) {
                        bool up = (((i & k) == 0) == asc);
                        unsigned a = key[base + i], b2_ = key[base + l];
                        unsigned lo = a < b2_ ? a : b2_, hi = a < b2_ ? b2_ : a;
                        key[base + i] = up ? lo : hi;
                        key[base + l] = up ? hi : lo;
                    }
                }
            }
        }
    };
    auto discard_merges = [&]() {              // per-lane top-8-of-32 into key[0..7]
#pragma unroll
        for (int i = 0; i < 8; ++i) key[i] = key[i] < key[8 + i] ? key[i] : key[8 + i];
#pragma unroll
        for (int jj = 4; jj > 0; jj >>= 1)
#pragma unroll
            for (int i = 0; i < 8; ++i) {
                int l = i ^ jj;
                if (l > i && key[l] < key[i]) { unsigned t2 = key[i]; key[i] = key[l]; key[l] = t2; }
            }
#pragma unroll
        for (int i = 0; i < 8; ++i) key[16 + i] = key[16 + i] < key[24 + i] ? key[16 + i] : key[24 + i];
#pragma unroll
        for (int jj = 4; jj > 0; jj >>= 1)
#pragma unroll
            for (int i = 0; i < 8; ++i) {
                int l = i ^ jj;
                if (l > i && key[16 + l] < key[16 + i]) { unsigned t2 = key[16 + i]; key[16 + i] = key[16 + l]; key[16 + l] = t2; }
            }
#pragma unroll
        for (int i = 0; i < 8; ++i) key[i] = key[i] < key[16 + 7 - i] ? key[i] : key[16 + 7 - i];
#pragma unroll
        for (int jj = 4; jj > 0; jj >>= 1)
#pragma unroll
            for (int i = 0; i < 8; ++i) {
                int l = i ^ jj;
                if (l > i && key[l] < key[i]) { unsigned t2 = key[i]; key[i] = key[l]; key[l] = t2; }
            }
    };
    unsigned k16[CAND];
    auto build16 = [&]() {                     // xor-1 butterfly: bitonic 16 -> sorted 16
        unsigned p8[8];
#pragma unroll
        for (int jj = 0; jj < 8; ++jj) p8[jj] = shx<1>(key[jj]);
#pragma unroll
        for (int jj = 0; jj < 8; ++jj) { k16[jj] = key[jj]; k16[8 + jj] = p8[7 - jj]; }
        clean16(k16);
    };
    auto finish_out = [&](int n) {
        int i16[CAND];
#pragma unroll
        for (int jj = 0; jj < CAND; ++jj) i16[jj] = __shfl((int)(k16[jj] & 0x7FFu), 0, 64);

        // gap test: can the proxy alone certify the top-8 SET?
        const float r7 = unflip(k16[7]), r8 = unflip(k16[8]);
        const float eps = fmaxf(fabsf(r7), fabsf(r8)) * 0.0009765625f + 2e-3f;  // 2^-10 rel + abs floor
        float ssum = 0.f;
        if (r8 - r7 > eps) {
            // fast path: proxy top-8 is exact; 8 gathers + sum
#pragma unroll
            for (int jj = 0; jj < KK; ++jj) ssum += xb[lane * NN + i16[jj]];
        } else {
            // slow path: exact fp64 rescore -> u64 keys -> pairwise rank
            const double qd = (double)xb[lane * NN + n];   // lane = channel
            u64 ke[CAND];
            float xf[CAND];
#pragma unroll
            for (int jj = 0; jj < CAND; ++jj) {
                const float xv = xb[lane * NN + i16[jj]];
                xf[jj] = xv;
                double dt = (double)xv - qd;
                double part = dt * dt;
                part += dppd<0xB1>(part);
                part += dppd<0x4E>(part);
                part += dppd<0x141>(part);
                part += dppd<0x140>(part);
                part += __shfl_xor(part, 16, 64);
                part += __shfl_xor(part, 32, 64);
                u64 eb = (u64)__double_as_longlong(part);  // identical on all lanes, >= 0
                ke[jj] = (eb & ~2047ull) | (u64)(unsigned)i16[jj];
            }
            int rank[CAND];
#pragma unroll
            for (int jj = 0; jj < CAND; ++jj) rank[jj] = 0;
#pragma unroll
            for (int jj = 0; jj < CAND; ++jj)
#pragma unroll
                for (int k2 = jj + 1; k2 < CAND; ++k2) {
                    const bool jw = ke[jj] < ke[k2];
                    rank[k2] += jw ? 1 : 0;
                    rank[jj] += jw ? 0 : 1;
                }
#pragma unroll
            for (int jj = 0; jj < CAND; ++jj) ssum += (rank[jj] < KK) ? xf[jj] : 0.f;
        }
        float mean = ssum * 0.125f;
        float* ob = out + b * (CC * 2 * NN) + lane * (2 * NN);
        ob[n]      = xb[lane * NN + n];   // first half: copy of x
        ob[NN + n] = mean;                // second half: mean of exact 8-NN features
    };

    // ================ item 0: plain phase A ================
    short8 afA[4];
    load_afrag(afA, n0a);
#pragma unroll
    for (int t8 = 0; t8 < TPW; ++t8) { tile_loads(t8); tile_mfma_epi(t8, afA, n0a); }
    __syncthreads();
    regload();                                  // item0 keys -> registers; LDS now free
    __syncthreads();

    // ================ fused: item1 phase A ∥ item0 select ================
    short8 afB[4];
    load_afrag(afB, n0b);
    tile_loads(0); sort8_grp(0);     tile_mfma_epi(0, afB, n0b);
    tile_loads(1); sort8_grp(1);     tile_mfma_epi(1, afB, n0b);
    tile_loads(2); sort8_grp(2);     tile_mfma_epi(2, afB, n0b);
    tile_loads(3); sort8_grp(3);     tile_mfma_epi(3, afB, n0b);
    tile_loads(4); discard_merges(); tile_mfma_epi(4, afB, n0b);
    tile_loads(5); build16();        tile_mfma_epi(5, afB, n0b);
    tile_loads(6); merge16<2>(k16);  merge16<7>(k16);                    tile_mfma_epi(6, afB, n0b);
    tile_loads(7); merge16<15>(k16); merge16<16>(k16); merge16<32>(k16); tile_mfma_epi(7, afB, n0b);
    finish_out(n0a + w);                        // output item0
    __syncthreads();                            // item1 keys all written

    // ================ item 1 select ================
    regload();
    sort8_grp(0); sort8_grp(1); sort8_grp(2); sort8_grp(3);
    discard_merges(); build16();
    merge16<2>(k16); merge16<7>(k16); merge16<15>(k16); merge16<16>(k16); merge16<32>(k16);
    finish_out(n0b + w);
}

extern "C" void kernel_launch(void* const* d_in, const int* in_sizes, int n_in,
                              void* d_out, int out_size, void* d_ws, size_t ws_size,
                              hipStream_t stream) {
    (void)in_sizes; (void)n_in; (void)ws_size; (void)out_size;
    const float* x = (const float*)d_in[0];
    float* xx = (float*)d_ws;                                        // 128 KB
    u16* bswz = (u16*)((char*)d_ws + (size_t)BB * NN * 4);           // 8 MB swizzled bf16 hi/lo
    float* out = (float*)d_out;
    compute_xx<<<dim3(BB * NN / 256), dim3(256), 0, stream>>>(x, xx);
    prep_bswz<<<dim3(BB * NTILE * 8 * 64 / 256), dim3(256), 0, stream>>>(x, bswz);
    knn_upsample<<<dim3(BB * NN / QB / 2), dim3(NT), 0, stream>>>(x, xx, bswz, out);
}

// Round 4
// 208.039 us; speedup vs baseline: 1.3955x; 1.3955x over previous
//
#include <hip/hip_runtime.h>
#include <math.h>

#define BB 16
#define CC 64
#define NN 2048
#define KK 8
#define CAND 16          // phase-1 candidates (exact top-8 subset; validated R3/R6/R7/R10-R17)
#define QB 8             // query rows in LDS (one per wave); keys LDS = QB*NN*4 = 64 KB
#define NT (QB * 64)     // 512 threads
#define MPW (NN / QB)    // 256 m-points per wave
#define TPW (MPW / 32)   // 8 col-tiles of 32 m-points per wave
#define NTILE (NN / 32)  // 64 m-tiles per batch
#define DPL 32           // keys per lane in select

typedef unsigned long long u64;
typedef unsigned short u16;
typedef __attribute__((ext_vector_type(8)))  short short8;   // 8 bf16 = 4 VGPRs (MFMA A/B frag)
typedef __attribute__((ext_vector_type(16))) float f32x16;   // MFMA 32x32 C/D frag

// order-preserving fp32 -> u32 flip: ascending uint == ascending float
__device__ __forceinline__ unsigned ordflip(float f) {
    unsigned u = __float_as_uint(f);
    return u ^ ((u & 0x80000000u) ? 0xFFFFFFFFu : 0x80000000u);
}
// inverse (on the masked high bits): recover approximate r from a packed key
__device__ __forceinline__ float unflip(unsigned k) {
    unsigned u = k & 0xFFFFF800u;
    u ^= (u & 0x80000000u) ? 0x80000000u : 0xFFFFFFFFu;
    return __uint_as_float(u);
}

// ---- cross-lane helpers: DPP for offsets inside a 16-lane row, bpermute beyond ----
template<int C>
__device__ __forceinline__ unsigned dppu(unsigned v) {
    return (unsigned)__builtin_amdgcn_update_dpp(0, (int)v, C, 0xF, 0xF, true);
}
template<int OFF>
__device__ __forceinline__ unsigned shx(unsigned v) {
    if constexpr (OFF == 1)       return dppu<0xB1>(v);    // quad_perm xor 1
    else if constexpr (OFF == 2)  return dppu<0x4E>(v);    // quad_perm xor 2
    else if constexpr (OFF == 7)  return dppu<0x141>(v);   // row_half_mirror = xor 7
    else if constexpr (OFF == 15) return dppu<0x140>(v);   // row_mirror      = xor 15
    else return (unsigned)__shfl_xor((int)v, OFF, 64);
}
template<int C>
__device__ __forceinline__ double dppd(double v) {
    unsigned long long u = (unsigned long long)__double_as_longlong(v);
    int lo = __builtin_amdgcn_update_dpp(0, (int)(u & 0xffffffffull), C, 0xF, 0xF, true);
    int hi = __builtin_amdgcn_update_dpp(0, (int)(u >> 32),           C, 0xF, 0xF, true);
    return __longlong_as_double((long long)(((unsigned long long)(unsigned)hi << 32) | (unsigned)lo));
}

// ascending bitonic cleanup of a bitonic 16-sequence (j = 8,4,2,1)
__device__ __forceinline__ void clean16(unsigned k[CAND]) {
#define CMPEX(a_, b_) { unsigned lo = k[a_] < k[b_] ? k[a_] : k[b_]; \
                        unsigned hi = k[a_] < k[b_] ? k[b_] : k[a_]; k[a_] = lo; k[b_] = hi; }
    CMPEX(0,8) CMPEX(1,9) CMPEX(2,10) CMPEX(3,11) CMPEX(4,12) CMPEX(5,13) CMPEX(6,14) CMPEX(7,15)
    CMPEX(0,4) CMPEX(1,5) CMPEX(2,6)  CMPEX(3,7)  CMPEX(8,12) CMPEX(9,13) CMPEX(10,14) CMPEX(11,15)
    CMPEX(0,2) CMPEX(1,3) CMPEX(4,6)  CMPEX(5,7)  CMPEX(8,10) CMPEX(9,11) CMPEX(12,14) CMPEX(13,15)
    CMPEX(0,1) CMPEX(2,3) CMPEX(4,5)  CMPEX(6,7)  CMPEX(8,9)  CMPEX(10,11) CMPEX(12,13) CMPEX(14,15)
#undef CMPEX
}

// one butterfly merge step: my sorted-16 vs partner's sorted-16 -> top-16 of union, sorted
template<int OFF>
__device__ __forceinline__ void merge16(unsigned k[CAND]) {
    unsigned pk[CAND];
#pragma unroll
    for (int j = 0; j < CAND; ++j) pk[j] = shx<OFF>(k[j]);
#pragma unroll
    for (int j = 0; j < CAND; ++j) {
        unsigned b2_ = pk[CAND - 1 - j];
        k[j] = (k[j] < b2_) ? k[j] : b2_;
    }
    clean16(k);
}

// per-lane top-8-of-32 + wave butterfly -> sorted wave top-16 in k16 (R2-verbatim)
__device__ __forceinline__ void select16(unsigned (&key)[DPL], unsigned (&k16)[CAND]) {
#pragma unroll
    for (int blk4 = 0; blk4 < 4; ++blk4) {
        const int base = blk4 * 8;
        const bool asc = (blk4 & 1) == 0;
#pragma unroll
        for (int k = 2; k <= 8; k <<= 1) {
#pragma unroll
            for (int jj = k >> 1; jj > 0; jj >>= 1) {
#pragma unroll
                for (int i = 0; i < 8; ++i) {
                    int l = i ^ jj;
                    if (l > i) {
                        bool up = (((i & k) == 0) == asc);
                        unsigned a = key[base + i], b2_ = key[base + l];
                        unsigned lo = a < b2_ ? a : b2_, hi = a < b2_ ? b2_ : a;
                        key[base + i] = up ? lo : hi;
                        key[base + l] = up ? hi : lo;
                    }
                }
            }
        }
    }
#pragma unroll
    for (int i = 0; i < 8; ++i) key[i] = key[i] < key[8 + i] ? key[i] : key[8 + i];
#pragma unroll
    for (int jj = 4; jj > 0; jj >>= 1)
#pragma unroll
        for (int i = 0; i < 8; ++i) {
            int l = i ^ jj;
            if (l > i && key[l] < key[i]) { unsigned t2 = key[i]; key[i] = key[l]; key[l] = t2; }
        }
#pragma unroll
    for (int i = 0; i < 8; ++i) key[16 + i] = key[16 + i] < key[24 + i] ? key[16 + i] : key[24 + i];
#pragma unroll
    for (int jj = 4; jj > 0; jj >>= 1)
#pragma unroll
        for (int i = 0; i < 8; ++i) {
            int l = i ^ jj;
            if (l > i && key[16 + l] < key[16 + i]) { unsigned t2 = key[16 + i]; key[16 + i] = key[16 + l]; key[16 + l] = t2; }
        }
#pragma unroll
    for (int i = 0; i < 8; ++i) key[i] = key[i] < key[16 + 7 - i] ? key[i] : key[16 + 7 - i];
#pragma unroll
    for (int jj = 4; jj > 0; jj >>= 1)
#pragma unroll
        for (int i = 0; i < 8; ++i) {
            int l = i ^ jj;
            if (l > i && key[l] < key[i]) { unsigned t2 = key[i]; key[i] = key[l]; key[l] = t2; }
        }
    // xor-1 butterfly: my-8 ++ reversed partner-8 = bitonic 16 -> sorted 16
    unsigned p8[8];
#pragma unroll
    for (int jj = 0; jj < 8; ++jj) p8[jj] = shx<1>(key[jj]);
#pragma unroll
    for (int jj = 0; jj < 8; ++jj) { k16[jj] = key[jj]; k16[8 + jj] = p8[7 - jj]; }
    clean16(k16);
    merge16<2>(k16);
    merge16<7>(k16);
    merge16<15>(k16);
    merge16<16>(k16);
    merge16<32>(k16);
}

// gap test + fast/slow path + output (R2-verbatim)
__device__ __forceinline__ void finish_out(const unsigned (&k16)[CAND], int n, int b,
                                           int lane, const float* __restrict__ xb,
                                           float* __restrict__ out) {
    int i16[CAND];
#pragma unroll
    for (int jj = 0; jj < CAND; ++jj) i16[jj] = __shfl((int)(k16[jj] & 0x7FFu), 0, 64);

    const float r7 = unflip(k16[7]), r8 = unflip(k16[8]);
    const float eps = fmaxf(fabsf(r7), fabsf(r8)) * 0.0009765625f + 2e-3f;  // 2^-10 rel + abs floor
    float ssum = 0.f;
    if (r8 - r7 > eps) {
        // fast path: proxy top-8 is exact; 8 gathers + sum
#pragma unroll
        for (int jj = 0; jj < KK; ++jj) ssum += xb[lane * NN + i16[jj]];
    } else {
        // slow path: exact fp64 rescore -> u64 keys -> pairwise rank
        const double qd = (double)xb[lane * NN + n];   // lane = channel
        u64 ke[CAND];
        float xf[CAND];
#pragma unroll
        for (int jj = 0; jj < CAND; ++jj) {
            const float xv = xb[lane * NN + i16[jj]];
            xf[jj] = xv;
            double dt = (double)xv - qd;
            double part = dt * dt;
            part += dppd<0xB1>(part);
            part += dppd<0x4E>(part);
            part += dppd<0x141>(part);
            part += dppd<0x140>(part);
            part += __shfl_xor(part, 16, 64);
            part += __shfl_xor(part, 32, 64);
            u64 eb = (u64)__double_as_longlong(part);  // identical on all lanes, >= 0
            ke[jj] = (eb & ~2047ull) | (u64)(unsigned)i16[jj];
        }
        int rank[CAND];
#pragma unroll
        for (int jj = 0; jj < CAND; ++jj) rank[jj] = 0;
#pragma unroll
        for (int jj = 0; jj < CAND; ++jj)
#pragma unroll
            for (int k2 = jj + 1; k2 < CAND; ++k2) {
                const bool jw = ke[jj] < ke[k2];
                rank[k2] += jw ? 1 : 0;
                rank[jj] += jw ? 0 : 1;
            }
#pragma unroll
        for (int jj = 0; jj < CAND; ++jj) ssum += (rank[jj] < KK) ? xf[jj] : 0.f;
    }
    float mean = ssum * 0.125f;
    float* ob = out + b * (CC * 2 * NN) + lane * (2 * NN);
    ob[n]      = xb[lane * NN + n];   // first half: copy of x
    ob[NN + n] = mean;                // second half: mean of exact 8-NN features
}

// Pre-swizzled split-bf16 MFMA operand store (R2) + fused xx reduction (R4):
// bswz unit index ((b*64 + tt)*8 + p*4 + ks)*64 + lane holds the EXACT 16B
// (8 bf16) that wave-lane `lane` consumes for m-tile tt, pass p (0=hi,1=lo),
// k-step ks: point n = tt*32 + (lane&31), channels ks*16 + (lane>>5)*8 .. +7.
// p==0 blocks also LDS-reduce the 8 per-point partial sums of squares -> xx,
// killing the separate compute_xx dispatch.
__global__ __launch_bounds__(256) void prep_bswz(const float* __restrict__ x,
                                                 u16* __restrict__ bswz,
                                                 float* __restrict__ xx) {
    __shared__ float red[256];
    const int t = blockIdx.x * 256 + threadIdx.x;   // [0, B*NTILE*8*64)
    const int lane = t & 63;
    const int ks   = (t >> 6) & 3;
    const int p    = (t >> 8) & 1;                  // = blockIdx.x & 1 (block-uniform)
    const int tt   = (t >> 9) & (NTILE - 1);
    const int b    = t >> 15;
    const int n    = tt * 32 + (lane & 31);
    const int c0   = ks * 16 + (lane >> 5) * 8;
    const float* src = x + b * (CC * NN) + n;
    unsigned o[8];
    float ss = 0.f;
#pragma unroll
    for (int i = 0; i < 8; ++i) {
        const float v = src[(c0 + i) * NN];           // 32 consecutive lanes -> 128B contiguous
        ss = fmaf(v, v, ss);
        unsigned u = __float_as_uint(v);
        unsigned hb = (u + 0x7FFFu + ((u >> 16) & 1u)) >> 16;       // RNE -> bf16 (hi)
        if (p == 0) {
            o[i] = hb;
        } else {
            const float vl = v - __uint_as_float(hb << 16);         // exact residual
            unsigned u2 = __float_as_uint(vl);
            o[i] = (u2 + 0x7FFFu + ((u2 >> 16) & 1u)) >> 16;        // RNE -> bf16 (lo)
        }
    }
    *(uint4*)(bswz + (size_t)t * 8) =
        make_uint4(o[0] | (o[1] << 16), o[2] | (o[3] << 16),
                   o[4] | (o[5] << 16), o[6] | (o[7] << 16));       // coalesced 16B store
    if (p == 0) {
        // point pt = lane&31 has 8 contributors at threadIdx = pt + 32*j, j=0..7
        red[threadIdx.x] = ss;
        __syncthreads();
        if (threadIdx.x < 32) {
            float s = red[threadIdx.x];
#pragma unroll
            for (int j2 = 1; j2 < 8; ++j2) s += red[threadIdx.x + j2 * 32];
            xx[b * NN + tt * 32 + threadIdx.x] = s;
        }
    }
}

// R4: dual-item MFMA packing. A rows 0-7 = item0 q_hi, 8-15 = item0 q_lo,
// 16-23 = item1 q_hi, 24-31 = item1 q_lo (R2 left rows 16-31 ZERO). The
// shared B passes (m_hi, m_lo) now serve 16 queries per 8 loads + 8 MFMAs
// per tile -> phase-A loads and MFMAs per query HALVE. C/D layout
// (HW-verified m74/m101 + R1/R2 pass): col=lane&31,
// row=(reg&3)+8*(reg>>2)+4*(lane>>5) -> lane half h holds item0 products of
// q=4h+r in regs r,r+4 and item1's in regs r+8,r+12: in-lane adds only.
// Item1 keys buffer in 32 regs (static idx), flushed to LDS before selects,
// so select-time pressure stays at R2's level (R3's spill: WRITE_SIZE 205MB).
__global__ __launch_bounds__(NT, 4) void knn_upsample(const float* __restrict__ x,
                                                      const float* __restrict__ xxg,
                                                      const u16* __restrict__ bswz,
                                                      float* __restrict__ out) {
    __shared__ unsigned keys[QB][NN];   // 64 KB

    const int tid  = threadIdx.x;
    const int w    = tid >> 6;                 // wave id = query row within item
    const int lane = tid & 63;
    const int blk  = blockIdx.x;

    // XCD-aware batch affinity (R13): 2048 blocks round-robin to 8 XCDs;
    // pin XCD x to batches {2x, 2x+1}.
    const int xcd = blk & 7;
    const int pj  = blk >> 3;                  // [0, 256)
    const int b   = 2 * xcd + (pj >> 7);       // batch
    const int jq  = pj & 127;                  // 16-query pair-group within batch
    const int n0a = jq << 4;                   // item0 query group
    const int n0b = n0a + 8;                   // item1 query group
    const float* xb = x + b * (CC * NN);

    const int col = lane & 31;                 // MFMA row/col index
    const int h   = lane >> 5;                 // k-half (channels 8h..8h+7 of each k-step)
    const int mbase = w * MPW;                 // 256 m-points per wave (tiles w*8 .. w*8+7)
    const u16* bp = bswz + (((size_t)b * NTILE + w * TPW) * 8) * 64 * 8 + lane * 8;
    const float* xxp = xxg + (b << 11);

    // A frags: col 0-7 item0-hi(q=col), 8-15 item0-lo, 16-23 item1-hi, 24-31 item1-lo
    short8 afrag[4];
    {
        const int qi = col & 7;
        const int p  = (col >> 3) & 1;         // hi/lo
        const int nq = n0a + (col >> 4) * 8 + qi;
        const u16* ap = bswz + ((((size_t)b * NTILE + (nq >> 5)) * 8 + p * 4) * 64
                                + h * 32 + (nq & 31)) * 8;
#pragma unroll
        for (int ks = 0; ks < 4; ++ks)
            afrag[ks] = *(const short8*)(ap + (size_t)ks * 64 * 8);
    }

    unsigned kb1[DPL];                         // item1 keys: 4 per tile x 8 tiles, static idx

#pragma unroll
    for (int t8 = 0; t8 < TPW; ++t8) {
        f32x16 acc1, acc2;                     // acc1: q*m_hi, acc2: q*m_lo (both items)
#pragma unroll
        for (int i2 = 0; i2 < 16; ++i2) { acc1[i2] = 0.f; acc2[i2] = 0.f; }
        short8 bv[4];                          // hi/lo halves split to cap live load regs
#pragma unroll
        for (int ks = 0; ks < 4; ++ks)
            bv[ks] = *(const short8*)(bp + ((size_t)(t8 * 8 + ks) * 64) * 8);
#pragma unroll
        for (int ks = 0; ks < 4; ++ks)
            acc1 = __builtin_amdgcn_mfma_f32_32x32x16_bf16(afrag[ks], bv[ks], acc1, 0, 0, 0);
#pragma unroll
        for (int ks = 0; ks < 4; ++ks)
            bv[ks] = *(const short8*)(bp + ((size_t)(t8 * 8 + 4 + ks) * 64) * 8);
#pragma unroll
        for (int ks = 0; ks < 4; ++ks)
            acc2 = __builtin_amdgcn_mfma_f32_32x32x16_bf16(afrag[ks], bv[ks], acc2, 0, 0, 0);

        const int m = mbase + t8 * 32 + col;
        const float xxm = xxp[m];
#pragma unroll
        for (int r = 0; r < 4; ++r) {
            const int q = 4 * h + r;           // lane half h owns query rows 4h..4h+3
            const float I0 = (acc1[r] + acc1[r + 4]) + (acc2[r] + acc2[r + 4]);
            const float r0 = fmaf(-2.f, I0, xxm);
            const unsigned u0 = ordflip(r0);
            keys[q][m] = (m == n0a + q) ? 0xFFFFFFFFu : ((u0 & 0xFFFFF800u) | (unsigned)m);
            const float I1 = (acc1[r + 8] + acc1[r + 12]) + (acc2[r + 8] + acc2[r + 12]);
            const float r1 = fmaf(-2.f, I1, xxm);
            const unsigned u1 = ordflip(r1);
            kb1[t8 * 4 + r] = (m == n0b + q) ? 0xFFFFFFFFu : ((u1 & 0xFFFFF800u) | (unsigned)m);
        }
    }
    __syncthreads();                           // item0 keys complete in LDS

    unsigned key[DPL];
#pragma unroll
    for (int t = 0; t < 8; ++t) {              // item0 keys -> regs (ds_read_b128)
        uint4 kv = *(const uint4*)(&keys[w][256 * t + 4 * lane]);
        key[4 * t] = kv.x; key[4 * t + 1] = kv.y; key[4 * t + 2] = kv.z; key[4 * t + 3] = kv.w;
    }
    __syncthreads();                           // all waves done reading item0 keys

    // flush item1 keys -> LDS (frees kb1 before any select pressure)
#pragma unroll
    for (int t8 = 0; t8 < TPW; ++t8)
#pragma unroll
        for (int r = 0; r < 4; ++r)
            keys[4 * h + r][mbase + t8 * 32 + col] = kb1[t8 * 4 + r];
    __syncthreads();                           // item1 keys complete

    // item0 select + output
    unsigned k16[CAND];
    select16(key, k16);
    finish_out(k16, n0a + w, b, lane, xb, out);

    // item1 select + output
#pragma unroll
    for (int t = 0; t < 8; ++t) {
        uint4 kv = *(const uint4*)(&keys[w][256 * t + 4 * lane]);
        key[4 * t] = kv.x; key[4 * t + 1] = kv.y; key[4 * t + 2] = kv.z; key[4 * t + 3] = kv.w;
    }
    select16(key, k16);
    finish_out(k16, n0b + w, b, lane, xb, out);
}

extern "C" void kernel_launch(void* const* d_in, const int* in_sizes, int n_in,
                              void* d_out, int out_size, void* d_ws, size_t ws_size,
                              hipStream_t stream) {
    (void)in_sizes; (void)n_in; (void)ws_size; (void)out_size;
    const float* x = (const float*)d_in[0];
    float* xx = (float*)d_ws;                                        // 128 KB
    u16* bswz = (u16*)((char*)d_ws + (size_t)BB * NN * 4);           // 8 MB swizzled bf16 hi/lo
    float* out = (float*)d_out;
    prep_bswz<<<dim3(BB * NTILE * 8 * 64 / 256), dim3(256), 0, stream>>>(x, bswz, xx);
    knn_upsample<<<dim3(BB * NN / QB / 2), dim3(NT), 0, stream>>>(x, xx, bswz, out);
}

// Round 5
// 193.311 us; speedup vs baseline: 1.5018x; 1.0762x over previous
//
#include <hip/hip_runtime.h>
#include <math.h>

#define BB 16
#define CC 64
#define NN 2048
#define KK 8
#define CAND 16          // phase-1 candidates (exact top-8 subset; validated R3/R6/R7/R10-R17)
#define QB 8             // query rows in LDS (one per wave); keys LDS = QB*NN*4 = 64 KB
#define NT (QB * 64)     // 512 threads
#define MPW (NN / QB)    // 256 m-points per wave
#define TPW (MPW / 32)   // 8 col-tiles of 32 m-points per wave
#define NTILE (NN / 32)  // 64 m-tiles per batch
#define DPL 32           // keys per lane in select

typedef unsigned long long u64;
typedef unsigned short u16;
typedef __attribute__((ext_vector_type(8)))  short short8;   // 8 bf16 = 4 VGPRs (MFMA A/B frag)
typedef __attribute__((ext_vector_type(16))) float f32x16;   // MFMA 32x32 C/D frag

// order-preserving fp32 -> u32 flip: ascending uint == ascending float
__device__ __forceinline__ unsigned ordflip(float f) {
    unsigned u = __float_as_uint(f);
    return u ^ ((u & 0x80000000u) ? 0xFFFFFFFFu : 0x80000000u);
}
// inverse (on the masked high bits): recover approximate r from a packed key
__device__ __forceinline__ float unflip(unsigned k) {
    unsigned u = k & 0xFFFFF800u;
    u ^= (u & 0x80000000u) ? 0x80000000u : 0xFFFFFFFFu;
    return __uint_as_float(u);
}

// ---- cross-lane helpers: DPP for offsets inside a 16-lane row, bpermute beyond ----
template<int C>
__device__ __forceinline__ unsigned dppu(unsigned v) {
    return (unsigned)__builtin_amdgcn_update_dpp(0, (int)v, C, 0xF, 0xF, true);
}
template<int OFF>
__device__ __forceinline__ unsigned shx(unsigned v) {
    if constexpr (OFF == 1)       return dppu<0xB1>(v);    // quad_perm xor 1
    else if constexpr (OFF == 2)  return dppu<0x4E>(v);    // quad_perm xor 2
    else if constexpr (OFF == 7)  return dppu<0x141>(v);   // row_half_mirror = xor 7
    else if constexpr (OFF == 15) return dppu<0x140>(v);   // row_mirror      = xor 15
    else return (unsigned)__shfl_xor((int)v, OFF, 64);
}
template<int C>
__device__ __forceinline__ double dppd(double v) {
    unsigned long long u = (unsigned long long)__double_as_longlong(v);
    int lo = __builtin_amdgcn_update_dpp(0, (int)(u & 0xffffffffull), C, 0xF, 0xF, true);
    int hi = __builtin_amdgcn_update_dpp(0, (int)(u >> 32),           C, 0xF, 0xF, true);
    return __longlong_as_double((long long)(((unsigned long long)(unsigned)hi << 32) | (unsigned)lo));
}

// ascending bitonic cleanup of a bitonic 16-sequence (j = 8,4,2,1)
__device__ __forceinline__ void clean16(unsigned k[CAND]) {
#define CMPEX(a_, b_) { unsigned lo = k[a_] < k[b_] ? k[a_] : k[b_]; \
                        unsigned hi = k[a_] < k[b_] ? k[b_] : k[a_]; k[a_] = lo; k[b_] = hi; }
    CMPEX(0,8) CMPEX(1,9) CMPEX(2,10) CMPEX(3,11) CMPEX(4,12) CMPEX(5,13) CMPEX(6,14) CMPEX(7,15)
    CMPEX(0,4) CMPEX(1,5) CMPEX(2,6)  CMPEX(3,7)  CMPEX(8,12) CMPEX(9,13) CMPEX(10,14) CMPEX(11,15)
    CMPEX(0,2) CMPEX(1,3) CMPEX(4,6)  CMPEX(5,7)  CMPEX(8,10) CMPEX(9,11) CMPEX(12,14) CMPEX(13,15)
    CMPEX(0,1) CMPEX(2,3) CMPEX(4,5)  CMPEX(6,7)  CMPEX(8,9)  CMPEX(10,11) CMPEX(12,13) CMPEX(14,15)
#undef CMPEX
}

// one butterfly merge step: my sorted-16 vs partner's sorted-16 -> top-16 of union, sorted
template<int OFF>
__device__ __forceinline__ void merge16(unsigned k[CAND]) {
    unsigned pk[CAND];
#pragma unroll
    for (int j = 0; j < CAND; ++j) pk[j] = shx<OFF>(k[j]);
#pragma unroll
    for (int j = 0; j < CAND; ++j) {
        unsigned b2_ = pk[CAND - 1 - j];
        k[j] = (k[j] < b2_) ? k[j] : b2_;
    }
    clean16(k);
}

// per-lane top-8-of-32 + wave butterfly -> sorted wave top-16 in k16 (R2-verbatim)
__device__ __forceinline__ void select16(unsigned (&key)[DPL], unsigned (&k16)[CAND]) {
#pragma unroll
    for (int blk4 = 0; blk4 < 4; ++blk4) {
        const int base = blk4 * 8;
        const bool asc = (blk4 & 1) == 0;
#pragma unroll
        for (int k = 2; k <= 8; k <<= 1) {
#pragma unroll
            for (int jj = k >> 1; jj > 0; jj >>= 1) {
#pragma unroll
                for (int i = 0; i < 8; ++i) {
                    int l = i ^ jj;
                    if (l > i) {
                        bool up = (((i & k) == 0) == asc);
                        unsigned a = key[base + i], b2_ = key[base + l];
                        unsigned lo = a < b2_ ? a : b2_, hi = a < b2_ ? b2_ : a;
                        key[base + i] = up ? lo : hi;
                        key[base + l] = up ? hi : lo;
                    }
                }
            }
        }
    }
#pragma unroll
    for (int i = 0; i < 8; ++i) key[i] = key[i] < key[8 + i] ? key[i] : key[8 + i];
#pragma unroll
    for (int jj = 4; jj > 0; jj >>= 1)
#pragma unroll
        for (int i = 0; i < 8; ++i) {
            int l = i ^ jj;
            if (l > i && key[l] < key[i]) { unsigned t2 = key[i]; key[i] = key[l]; key[l] = t2; }
        }
#pragma unroll
    for (int i = 0; i < 8; ++i) key[16 + i] = key[16 + i] < key[24 + i] ? key[16 + i] : key[24 + i];
#pragma unroll
    for (int jj = 4; jj > 0; jj >>= 1)
#pragma unroll
        for (int i = 0; i < 8; ++i) {
            int l = i ^ jj;
            if (l > i && key[16 + l] < key[16 + i]) { unsigned t2 = key[16 + i]; key[16 + i] = key[16 + l]; key[16 + l] = t2; }
        }
#pragma unroll
    for (int i = 0; i < 8; ++i) key[i] = key[i] < key[16 + 7 - i] ? key[i] : key[16 + 7 - i];
#pragma unroll
    for (int jj = 4; jj > 0; jj >>= 1)
#pragma unroll
        for (int i = 0; i < 8; ++i) {
            int l = i ^ jj;
            if (l > i && key[l] < key[i]) { unsigned t2 = key[i]; key[i] = key[l]; key[l] = t2; }
        }
    // xor-1 butterfly: my-8 ++ reversed partner-8 = bitonic 16 -> sorted 16
    unsigned p8[8];
#pragma unroll
    for (int jj = 0; jj < 8; ++jj) p8[jj] = shx<1>(key[jj]);
#pragma unroll
    for (int jj = 0; jj < 8; ++jj) { k16[jj] = key[jj]; k16[8 + jj] = p8[7 - jj]; }
    clean16(k16);
    merge16<2>(k16);
    merge16<7>(k16);
    merge16<15>(k16);
    merge16<16>(k16);
    merge16<32>(k16);
}

// gap test + fast/slow path; mean lands in LDS (R5: coalesced flush at block end)
__device__ __forceinline__ void finish_mean(const unsigned (&k16)[CAND], int n, int qq,
                                            int lane, const float* __restrict__ xb,
                                            float (*ldsm)[18]) {
    int i16[CAND];
#pragma unroll
    for (int jj = 0; jj < CAND; ++jj) i16[jj] = __shfl((int)(k16[jj] & 0x7FFu), 0, 64);

    const float r7 = unflip(k16[7]), r8 = unflip(k16[8]);
    const float eps = fmaxf(fabsf(r7), fabsf(r8)) * 0.0009765625f + 2e-3f;  // 2^-10 rel + abs floor
    float ssum = 0.f;
    if (r8 - r7 > eps) {
        // fast path: proxy top-8 is exact; 8 gathers + sum
#pragma unroll
        for (int jj = 0; jj < KK; ++jj) ssum += xb[lane * NN + i16[jj]];
    } else {
        // slow path: exact fp64 rescore -> u64 keys -> pairwise rank
        const double qd = (double)xb[lane * NN + n];   // lane = channel
        u64 ke[CAND];
        float xf[CAND];
#pragma unroll
        for (int jj = 0; jj < CAND; ++jj) {
            const float xv = xb[lane * NN + i16[jj]];
            xf[jj] = xv;
            double dt = (double)xv - qd;
            double part = dt * dt;
            part += dppd<0xB1>(part);
            part += dppd<0x4E>(part);
            part += dppd<0x141>(part);
            part += dppd<0x140>(part);
            part += __shfl_xor(part, 16, 64);
            part += __shfl_xor(part, 32, 64);
            u64 eb = (u64)__double_as_longlong(part);  // identical on all lanes, >= 0
            ke[jj] = (eb & ~2047ull) | (u64)(unsigned)i16[jj];
        }
        int rank[CAND];
#pragma unroll
        for (int jj = 0; jj < CAND; ++jj) rank[jj] = 0;
#pragma unroll
        for (int jj = 0; jj < CAND; ++jj)
#pragma unroll
            for (int k2 = jj + 1; k2 < CAND; ++k2) {
                const bool jw = ke[jj] < ke[k2];
                rank[k2] += jw ? 1 : 0;
                rank[jj] += jw ? 0 : 1;
            }
#pragma unroll
        for (int jj = 0; jj < CAND; ++jj) ssum += (rank[jj] < KK) ? xf[jj] : 0.f;
    }
    ldsm[lane][qq] = ssum * 0.125f;     // [64][18] pad -> 2-way bank alias only (free, m136)
}

// Pre-swizzled split-bf16 MFMA operand store (R2) + fused xx reduction (R4) +
// coalesced out-first-half copy (R5): bswz unit index
// ((b*64 + tt)*8 + p*4 + ks)*64 + lane holds the EXACT 16B (8 bf16) that
// wave-lane `lane` consumes for m-tile tt, pass p (0=hi,1=lo), k-step ks:
// point n = tt*32 + (lane&31), channels ks*16 + (lane>>5)*8 .. +7.
// p==0 blocks additionally write out[b][c][0..N) = x (128B contiguous per
// 32-lane group), removing the scattered per-lane copy store from the main
// kernel, and LDS-reduce the per-point sums of squares -> xx.
__global__ __launch_bounds__(256) void prep_bswz(const float* __restrict__ x,
                                                 u16* __restrict__ bswz,
                                                 float* __restrict__ xx,
                                                 float* __restrict__ out) {
    __shared__ float red[256];
    const int t = blockIdx.x * 256 + threadIdx.x;   // [0, B*NTILE*8*64)
    const int lane = t & 63;
    const int ks   = (t >> 6) & 3;
    const int p    = (t >> 8) & 1;                  // = blockIdx.x & 1 (block-uniform)
    const int tt   = (t >> 9) & (NTILE - 1);
    const int b    = t >> 15;
    const int n    = tt * 32 + (lane & 31);
    const int c0   = ks * 16 + (lane >> 5) * 8;
    const float* src = x + b * (CC * NN) + n;
    unsigned o[8];
    float vv[8];
    float ss = 0.f;
#pragma unroll
    for (int i = 0; i < 8; ++i) {
        const float v = src[(c0 + i) * NN];           // 32 consecutive lanes -> 128B contiguous
        vv[i] = v;
        ss = fmaf(v, v, ss);
        unsigned u = __float_as_uint(v);
        unsigned hb = (u + 0x7FFFu + ((u >> 16) & 1u)) >> 16;       // RNE -> bf16 (hi)
        if (p == 0) {
            o[i] = hb;
        } else {
            const float vl = v - __uint_as_float(hb << 16);         // exact residual
            unsigned u2 = __float_as_uint(vl);
            o[i] = (u2 + 0x7FFFu + ((u2 >> 16) & 1u)) >> 16;        // RNE -> bf16 (lo)
        }
    }
    *(uint4*)(bswz + (size_t)t * 8) =
        make_uint4(o[0] | (o[1] << 16), o[2] | (o[3] << 16),
                   o[4] | (o[5] << 16), o[6] | (o[7] << 16));       // coalesced 16B store
    if (p == 0) {
        // out first half: out[b][c][n] = x[b][c][n] (coalesced 128B segments)
        float* ob = out + (size_t)b * (CC * 2 * NN) + n;
#pragma unroll
        for (int i = 0; i < 8; ++i) ob[(size_t)(c0 + i) * (2 * NN)] = vv[i];
        // point pt = lane&31 has 8 contributors at threadIdx = pt + 32*j, j=0..7
        red[threadIdx.x] = ss;
        __syncthreads();
        if (threadIdx.x < 32) {
            float s = red[threadIdx.x];
#pragma unroll
            for (int j2 = 1; j2 < 8; ++j2) s += red[threadIdx.x + j2 * 32];
            xx[b * NN + tt * 32 + threadIdx.x] = s;
        }
    }
}

// R4 structure + R5 epilogue offload. Dual-item MFMA packing: A rows 0-7 =
// item0 q_hi, 8-15 = item0 q_lo, 16-23 = item1 q_hi, 24-31 = item1 q_lo; the
// shared B passes serve 16 queries per 8 loads + 8 MFMAs per tile. C/D layout
// (HW-verified m74/m101 + R1/R2 pass): col=lane&31,
// row=(reg&3)+8*(reg>>2)+4*(lane>>5) -> lane half h holds item0 products of
// q=4h+r in regs r,r+4 and item1's in regs r+8,r+12: in-lane adds only.
// R5: B-fragment loads explicitly double-buffered (bva/bvb rotation) so the
// next tile's hi-half is in flight under the current tile's MFMAs; means are
// staged in LDS and flushed coalesced; the x-copy store moved to prep_bswz.
__global__ __launch_bounds__(NT, 4) void knn_upsample(const float* __restrict__ x,
                                                      const float* __restrict__ xxg,
                                                      const u16* __restrict__ bswz,
                                                      float* __restrict__ out) {
    __shared__ unsigned keys[QB][NN];   // 64 KB
    __shared__ float lds_mean[64][18];  // [channel][query-in-block], pad 18 -> 2-way alias only

    const int tid  = threadIdx.x;
    const int w    = tid >> 6;                 // wave id = query row within item
    const int lane = tid & 63;
    const int blk  = blockIdx.x;

    // XCD-aware batch affinity (R13): 2048 blocks round-robin to 8 XCDs;
    // pin XCD x to batches {2x, 2x+1}.
    const int xcd = blk & 7;
    const int pj  = blk >> 3;                  // [0, 256)
    const int b   = 2 * xcd + (pj >> 7);       // batch
    const int jq  = pj & 127;                  // 16-query pair-group within batch
    const int n0a = jq << 4;                   // item0 query group
    const int n0b = n0a + 8;                   // item1 query group
    const float* xb = x + b * (CC * NN);

    const int col = lane & 31;                 // MFMA row/col index
    const int h   = lane >> 5;                 // k-half (channels 8h..8h+7 of each k-step)
    const int mbase = w * MPW;                 // 256 m-points per wave (tiles w*8 .. w*8+7)
    const u16* bp = bswz + (((size_t)b * NTILE + w * TPW) * 8) * 64 * 8 + lane * 8;
    const float* xxp = xxg + (b << 11);

    // A frags: col 0-7 item0-hi(q=col), 8-15 item0-lo, 16-23 item1-hi, 24-31 item1-lo
    short8 afrag[4];
    {
        const int qi = col & 7;
        const int p  = (col >> 3) & 1;         // hi/lo
        const int nq = n0a + (col >> 4) * 8 + qi;
        const u16* ap = bswz + ((((size_t)b * NTILE + (nq >> 5)) * 8 + p * 4) * 64
                                + h * 32 + (nq & 31)) * 8;
#pragma unroll
        for (int ks = 0; ks < 4; ++ks)
            afrag[ks] = *(const short8*)(ap + (size_t)ks * 64 * 8);
    }

#define LOADB(t8_, slot_) (*(const short8*)(bp + ((size_t)((t8_) * 8 + (slot_)) * 64) * 8))

    unsigned kb1[DPL];                         // item1 keys: 4 per tile x 8 tiles, static idx
    short8 bva[4], bvb[4];
#pragma unroll
    for (int ks = 0; ks < 4; ++ks) bva[ks] = LOADB(0, ks);   // prologue: tile0 hi

#pragma unroll
    for (int t8 = 0; t8 < TPW; ++t8) {
        f32x16 acc1, acc2;                     // acc1: q*m_hi, acc2: q*m_lo (both items)
#pragma unroll
        for (int i2 = 0; i2 < 16; ++i2) { acc1[i2] = 0.f; acc2[i2] = 0.f; }
#pragma unroll
        for (int ks = 0; ks < 4; ++ks) bvb[ks] = LOADB(t8, 4 + ks);      // lo of t8
#pragma unroll
        for (int ks = 0; ks < 4; ++ks)
            acc1 = __builtin_amdgcn_mfma_f32_32x32x16_bf16(afrag[ks], bva[ks], acc1, 0, 0, 0);
        if (t8 < TPW - 1) {
#pragma unroll
            for (int ks = 0; ks < 4; ++ks) bva[ks] = LOADB(t8 + 1, ks);  // hi of t8+1 in flight
        }
#pragma unroll
        for (int ks = 0; ks < 4; ++ks)
            acc2 = __builtin_amdgcn_mfma_f32_32x32x16_bf16(afrag[ks], bvb[ks], acc2, 0, 0, 0);

        const int m = mbase + t8 * 32 + col;
        const float xxm = xxp[m];
#pragma unroll
        for (int r = 0; r < 4; ++r) {
            const int q = 4 * h + r;           // lane half h owns query rows 4h..4h+3
            const float I0 = (acc1[r] + acc1[r + 4]) + (acc2[r] + acc2[r + 4]);
            const float r0 = fmaf(-2.f, I0, xxm);
            const unsigned u0 = ordflip(r0);
            keys[q][m] = (m == n0a + q) ? 0xFFFFFFFFu : ((u0 & 0xFFFFF800u) | (unsigned)m);
            const float I1 = (acc1[r + 8] + acc1[r + 12]) + (acc2[r + 8] + acc2[r + 12]);
            const float r1 = fmaf(-2.f, I1, xxm);
            const unsigned u1 = ordflip(r1);
            kb1[t8 * 4 + r] = (m == n0b + q) ? 0xFFFFFFFFu : ((u1 & 0xFFFFF800u) | (unsigned)m);
        }
    }
#undef LOADB
    __syncthreads();                           // item0 keys complete in LDS

    unsigned key[DPL];
#pragma unroll
    for (int t = 0; t < 8; ++t) {              // item0 keys -> regs (ds_read_b128)
        uint4 kv = *(const uint4*)(&keys[w][256 * t + 4 * lane]);
        key[4 * t] = kv.x; key[4 * t + 1] = kv.y; key[4 * t + 2] = kv.z; key[4 * t + 3] = kv.w;
    }
    __syncthreads();                           // all waves done reading item0 keys

    // flush item1 keys -> LDS (frees kb1 before any select pressure)
#pragma unroll
    for (int t8 = 0; t8 < TPW; ++t8)
#pragma unroll
        for (int r = 0; r < 4; ++r)
            keys[4 * h + r][mbase + t8 * 32 + col] = kb1[t8 * 4 + r];
    __syncthreads();                           // item1 keys complete

    // item0 select + mean -> LDS
    unsigned k16[CAND];
    select16(key, k16);
    finish_mean(k16, n0a + w, w, lane, xb, lds_mean);

    // item1 select + mean -> LDS
#pragma unroll
    for (int t = 0; t < 8; ++t) {
        uint4 kv = *(const uint4*)(&keys[w][256 * t + 4 * lane]);
        key[4 * t] = kv.x; key[4 * t + 1] = kv.y; key[4 * t + 2] = kv.z; key[4 * t + 3] = kv.w;
    }
    select16(key, k16);
    finish_mean(k16, n0b + w, 8 + w, lane, xb, lds_mean);

    __syncthreads();                           // all 16 query means staged

    // coalesced flush: out[b][c][N + n0a + qq], 16 consecutive floats per channel.
    // thread -> (c = tid>>3, qq = (tid&7)*2): float2 per thread, 64B per channel row.
    {
        const int c  = tid >> 3;
        const int q2 = (tid & 7) << 1;
        float2 mv = *(const float2*)&lds_mean[c][q2];
        *(float2*)(out + (size_t)b * (CC * 2 * NN) + (size_t)c * (2 * NN) + NN + n0a + q2) = mv;
    }
}

extern "C" void kernel_launch(void* const* d_in, const int* in_sizes, int n_in,
                              void* d_out, int out_size, void* d_ws, size_t ws_size,
                              hipStream_t stream) {
    (void)in_sizes; (void)n_in; (void)ws_size; (void)out_size;
    const float* x = (const float*)d_in[0];
    float* xx = (float*)d_ws;                                        // 128 KB
    u16* bswz = (u16*)((char*)d_ws + (size_t)BB * NN * 4);           // 8 MB swizzled bf16 hi/lo
    float* out = (float*)d_out;
    prep_bswz<<<dim3(BB * NTILE * 8 * 64 / 256), dim3(256), 0, stream>>>(x, bswz, xx, out);
    knn_upsample<<<dim3(BB * NN / QB / 2), dim3(NT), 0, stream>>>(x, xx, bswz, out);
}